// Round 7
// baseline (66.852 us; speedup 1.0000x reference)
//
#include <hip/hip_runtime.h>

// Phase vocoder (fixed rate 1.2) + abs() of complex result == magnitude interp:
//   out[row,t] = a * n[idx+1] + (1-a) * n[idx],  n[k] = |spec[row,k]|, n[2048]=0
// RATE = 12/10 exactly: unit u (10 outputs) consumes exactly inputs [12u,12u+12).
// floor(1.2*s), s=0..9 is the static table {0,1,2,3,4,6,7,8,9,10}.
//
// R6 lesson: per-lane 48B-stride float4 loads cause ~3x L1 line-lookup
// amplification. Fix: 4-lane groups load their shared 192B window DENSELY
// (lane j takes float4 {j, j+4, j+8}), compute norms in dense layout, then
// two shfl_xor rounds redistribute norm-vec4s so lane j owns n[12j..12j+12)
// of the group window. Output path (wave-private LDS transpose + coalesced
// nontemporal float4 stores) unchanged from R6.

#define T_IN   2048
#define T_OUT  1707
#define UPT    10            // outputs per unit
#define IPT    12            // inputs per unit
#define UPR    171           // units per row; unit 170 emits only 7 outputs

typedef float vf4 __attribute__((ext_vector_type(4)));
typedef float vf2 __attribute__((ext_vector_type(2)));

__global__ __launch_bounds__(192) void pv_dense_kernel(
    const float* __restrict__ re, const float* __restrict__ im,
    float* __restrict__ out) {
    __shared__ __align__(16) float lds[3][640];  // wave-private transpose scratch

    const int row  = blockIdx.x;
    const int tid  = threadIdx.x;     // == unit index vr (incl. phantom 171..191)
    const int wv   = tid >> 6;
    const int lane = tid & 63;
    const int G    = tid >> 2;        // 4-lane group, 0..47
    const int j    = tid & 3;         // slot within group

    const float* __restrict__ rbase = re + (size_t)row * T_IN;
    const float* __restrict__ ibase = im + (size_t)row * T_IN;

    // ---- dense grouped loads: float4 at 48G + 4j + 16p, p = 0..2 ----
    float4 ra[3], ia[3];
#pragma unroll
    for (int p = 0; p < 3; ++p) {
        int f = 48 * G + 4 * j + 16 * p;
        if (f < T_IN) {               // OOB (group 42 p=2 / phantom groups) -> 0
            ra[p] = *(const float4*)(rbase + f);
            ia[p] = *(const float4*)(ibase + f);
        } else {
            ra[p] = make_float4(0.f, 0.f, 0.f, 0.f);
            ia[p] = make_float4(0.f, 0.f, 0.f, 0.f);
        }
    }

    // ---- norms in dense layout: lane holds window-vec4s W_j, W_{j+4}, W_{j+8}
    float n0[4], n1[4], n2[4];
    {
        const float* r0 = &ra[0].x; const float* q0 = &ia[0].x;
        const float* r1 = &ra[1].x; const float* q1 = &ia[1].x;
        const float* r2 = &ra[2].x; const float* q2 = &ia[2].x;
#pragma unroll
        for (int k = 0; k < 4; ++k) {
            n0[k] = sqrtf(r0[k] * r0[k] + q0[k] * q0[k]);
            n1[k] = sqrtf(r1[k] * r1[k] + q1[k] * q1[k]);
            n2[k] = sqrtf(r2[k] * r2[k] + q2[k] * q2[k]);
        }
    }

    // ---- redistribute: lane j needs W_{3j}, W_{3j+1}, W_{3j+2} ----
    // round 1 (xor 1): send {j0:m1, j1:m0, j2:m2, j3:m1} -> recv = middle vec B
    // round 2 (xor 2): send {j0:m2, j1:m2, j2:m0, j3:m0} -> recv = A or C part
    float n[IPT];
#pragma unroll
    for (int k = 0; k < 4; ++k) {
        float s1 = (j == 0) ? n1[k] : (j == 1) ? n0[k] : (j == 2) ? n2[k] : n1[k];
        float B  = __shfl_xor(s1, 1);
        float s2 = (j < 2) ? n2[k] : n0[k];
        float r2 = __shfl_xor(s2, 2);
        float A  = (j & 1) ? r2 : ((j == 0) ? n0[k] : n1[k]);
        float C  = (j & 1) ? ((j == 1) ? n1[k] : n2[k]) : r2;
        n[k] = A; n[4 + k] = B; n[8 + k] = C;
    }

    // ---- lerp (static floor table) + park in wave's LDS slice ----
    const int vr = tid;               // unit index within row
    if (vr < UPR) {
        const int L[UPT] = {0, 1, 2, 3, 4, 6, 7, 8, 9, 10};
        const float tb = (float)(IPT * vr);        // exact integer
        float o[UPT];
#pragma unroll
        for (int s = 0; s < UPT; ++s) {
            float tf = (float)(UPT * vr + s) * 1.2f;  // matches ref time_steps
            float a  = tf - (tb + (float)L[s]);       // == tf - floor(tf)
            o[s] = a * n[L[s] + 1] + (1.0f - a) * n[L[s]];
        }
        float* slice = lds[wv];
#pragma unroll
        for (int s2 = 0; s2 < 5; ++s2) {
            vf2 v; v.x = o[2 * s2]; v.y = o[2 * s2 + 1];
            *(vf2*)&slice[UPT * lane + 2 * s2] = v;
        }
    }

    // ---- lane-major coalesced nt stores of the wave's contiguous span ----
    const int u0  = wv << 6;
    const int cnt = (u0 + 64 < UPR) ? 640 : (T_OUT - UPT * u0);  // 640/640/427
    float* __restrict__ gbase = out + (size_t)row * T_OUT + (size_t)(UPT * u0);
    const float* slice = lds[wv];
#pragma unroll
    for (int p = 0; p < 3; ++p) {
        int off = (p << 8) + (lane << 2);
        if (off + 4 <= cnt) {
            vf4 v = *(const vf4*)&slice[off];
            __builtin_nontemporal_store(v, (vf4*)(gbase + off));
        } else if (off < cnt) {
            for (int t = off; t < cnt; ++t)
                __builtin_nontemporal_store(slice[t], gbase + t);
        }
    }
}

extern "C" void kernel_launch(void* const* d_in, const int* in_sizes, int n_in,
                              void* d_out, int out_size, void* d_ws, size_t ws_size,
                              hipStream_t stream) {
    const float* re = (const float*)d_in[0];
    const float* im = (const float*)d_in[1];
    float* out = (float*)d_out;

    const int nrows = in_sizes[0] / T_IN;    // 16 * 1025 = 16400
    pv_dense_kernel<<<nrows, 192, 0, stream>>>(re, im, out);
}

// Round 8
// 60.655 us; speedup vs baseline: 1.1022x; 1.1022x over previous
//
#include <hip/hip_runtime.h>

// Phase vocoder (fixed rate 1.2) + abs() of complex result == magnitude interp:
//   out[row,t] = a * n[idx+1] + (1-a) * n[idx],  n[k] = |spec[row,k]|, n[2048]=0
// RATE = 12/10 exactly: unit u (10 outputs t=10u..10u+9) consumes exactly
// inputs [12u, 12u+12); floor(1.2*s), s=0..9 = static {0,1,2,3,4,6,7,8,9,10}.
//
// All three phases at optimal transaction counts:
//  A: dense float4 global loads (1KB contiguous per wave-instr),
//     ds_write_b128 @16B stride (conflict-free), barrier.
//  B: 3x ds_read_b128 @48B lane stride (8 lanes tile 32 banks: conflict-free),
//     static-table lerp, vf2 LDS park @40B stride (16 lanes tile 32 banks).
//  C: same-wave dense vf4 nontemporal stores (lgkmcnt(0) covers the
//     cross-lane same-wave LDS dep; nt keeps the write stream out of L3 so
//     ~half the input stays L3-resident across replays -> FETCH ~131MB).

#define T_IN   2048
#define T_OUT  1707
#define UPT    10
#define IPT    12
#define UPR    171           // units per row; unit 170 emits only 7 outputs

typedef float vf4 __attribute__((ext_vector_type(4)));
typedef float vf2 __attribute__((ext_vector_type(2)));

__global__ __launch_bounds__(256) void pv_lds_kernel(
    const float* __restrict__ re, const float* __restrict__ im,
    float* __restrict__ out) {
    __shared__ __align__(16) float n[T_IN + 16];   // norms + zero pad
    __shared__ __align__(16) float ob[3][640];     // per-wave output transpose

    const int row  = blockIdx.x;
    const int tid  = threadIdx.x;
    const int wv   = tid >> 6;
    const int lane = tid & 63;

    const float4* __restrict__ re4 = (const float4*)(re + (size_t)row * T_IN);
    const float4* __restrict__ im4 = (const float4*)(im + (size_t)row * T_IN);

    // ---- Phase A: dense staging of norms ----
#pragma unroll
    for (int k = 0; k < 2; ++k) {
        int v = (k << 8) + tid;          // float4 index 0..511
        float4 r = re4[v];
        float4 q = im4[v];
        vf4 m;
        m.x = sqrtf(r.x * r.x + q.x * q.x);
        m.y = sqrtf(r.y * r.y + q.y * q.y);
        m.z = sqrtf(r.z * r.z + q.z * q.z);
        m.w = sqrtf(r.w * r.w + q.w * q.w);
        *(vf4*)&n[v << 2] = m;
    }
    if (tid < 4) {                       // zero pad n[2048..2063]
        vf4 z = {0.f, 0.f, 0.f, 0.f};
        *(vf4*)&n[T_IN + (tid << 2)] = z;
    }
    __syncthreads();

    // ---- Phase B: unit-based lerp, vectorized LDS reads ----
    if (tid < UPR) {
        const int u = tid;
        vf4 na = *(const vf4*)&n[IPT * u];
        vf4 nb = *(const vf4*)&n[IPT * u + 4];
        vf4 nc = *(const vf4*)&n[IPT * u + 8];
        float nn[IPT];
        nn[0]=na.x; nn[1]=na.y; nn[2] =na.z; nn[3] =na.w;
        nn[4]=nb.x; nn[5]=nb.y; nn[6] =nb.z; nn[7] =nb.w;
        nn[8]=nc.x; nn[9]=nc.y; nn[10]=nc.z; nn[11]=nc.w;

        const int L[UPT] = {0, 1, 2, 3, 4, 6, 7, 8, 9, 10};
        const float tb = (float)(IPT * u);          // exact integer
        float o[UPT];
#pragma unroll
        for (int s = 0; s < UPT; ++s) {
            float tf = (float)(UPT * u + s) * 1.2f; // matches ref time_steps
            float a  = tf - (tb + (float)L[s]);     // == tf - floor(tf)
            o[s] = a * nn[L[s] + 1] + (1.0f - a) * nn[L[s]];
        }
        float* slice = ob[wv];
#pragma unroll
        for (int s2 = 0; s2 < 5; ++s2) {
            vf2 v2; v2.x = o[2 * s2]; v2.y = o[2 * s2 + 1];
            *(vf2*)&slice[UPT * lane + 2 * s2] = v2;
        }
    }

    // same-wave cross-lane LDS dep: drain this wave's ds ops
    asm volatile("s_waitcnt lgkmcnt(0)" ::: "memory");

    // ---- Phase C: dense nt stores of each wave's contiguous span ----
    if (wv < 3) {
        const int u0  = wv << 6;
        const int cnt = (wv < 2) ? 640 : (T_OUT - UPT * u0);  // 640,640,427
        float* __restrict__ gbase = out + (size_t)row * T_OUT + (size_t)(UPT * u0);
        const float* slice = ob[wv];
#pragma unroll
        for (int p = 0; p < 3; ++p) {
            int off = (p << 8) + (lane << 2);
            if (off + 4 <= cnt) {
                vf4 v = *(const vf4*)&slice[off];
                __builtin_nontemporal_store(v, (vf4*)(gbase + off));
            } else if (off < cnt) {
                for (int t = off; t < cnt; ++t)
                    __builtin_nontemporal_store(slice[t], gbase + t);
            }
        }
    }
}

extern "C" void kernel_launch(void* const* d_in, const int* in_sizes, int n_in,
                              void* d_out, int out_size, void* d_ws, size_t ws_size,
                              hipStream_t stream) {
    const float* re = (const float*)d_in[0];
    const float* im = (const float*)d_in[1];
    float* out = (float*)d_out;

    const int nrows = in_sizes[0] / T_IN;    // 16 * 1025 = 16400
    pv_lds_kernel<<<nrows, 256, 0, stream>>>(re, im, out);
}